// Round 6
// baseline (722.814 us; speedup 1.0000x reference)
//
#include <hip/hip_runtime.h>
#include <hip/hip_fp16.h>

// Stacked GRU (T=50, B=1, H=256) on MI355X — round 18.
// r17 skeleton (same-XCD L2 exchange, dual publish). One change:
//  - LEAN FAST POLL: spin purely on sc0 L2 loads (self-throttled ~250cy by
//    serialized vmcnt(0)); the MALL fallback ald + s_sleep are demoted to
//    the i>32 slow path (insurance only, every 16th iter).
//    r17's poll interleaved a ~900cy MALL ald every 4th iter INSIDE the
//    loop — during finalize-overlap polling this stalled detection of
//    already-arrived L2 data by ~400-500cy per exchange.
// r17 lesson: same-XCD sc0 store->load via the shared L2 is coherent and
//   ~4x faster than MALL; posts (other XCDs) must use the MALL copy.
// r13 lesson: detection rides WITH data (one transaction) — kept.
// r12 lesson: no RMWs near exchange lines — kept.
// r15 lesson: don't flood the MALL exchange lines — kept (MALL checks rare).

#define T_STEPS 50
#define VIN 768
#define VF 128
#define MIN_ 2
#define H 256
#define G3 768

#define NB 32
#define BT 256
#define HJ 8
#define BAIL 4000000
#define NBLOCKS 264

typedef unsigned long long u64;
#define POISON64 0xFFFFFFFFFFFFFFFFull

__device__ __forceinline__ float sigm(float x){
  x = fminf(fmaxf(x, -30.f), 30.f);
  return __builtin_amdgcn_rcpf(1.f + __expf(-x));
}
__device__ __forceinline__ float ftanh(float x){
  x = fminf(fmaxf(x, -9.f), 9.f);
  float e = __expf(2.f*x);
  return (e - 1.f) * __builtin_amdgcn_rcpf(e + 1.f);
}
__device__ __forceinline__ float eluf(float x){ return x > 0.0f ? x : expm1f(x); }

__device__ __forceinline__ u64 ald(const u64* p){
  return __hip_atomic_load(const_cast<u64*>(p), __ATOMIC_RELAXED, __HIP_MEMORY_SCOPE_AGENT);
}
__device__ __forceinline__ unsigned ald32(const unsigned* p){
  return __hip_atomic_load(const_cast<unsigned*>(p), __ATOMIC_RELAXED, __HIP_MEMORY_SCOPE_AGENT);
}
__device__ __forceinline__ void ast(u64* p, u64 v){
  __hip_atomic_store(p, v, __ATOMIC_RELAXED, __HIP_MEMORY_SCOPE_AGENT);
}
__device__ __forceinline__ u64 packtv(unsigned tag, float v){
  union{ float f; unsigned u; } c; c.f = v;
  return ((u64)tag << 32) | (u64)c.u;
}
__device__ __forceinline__ float unpackv(u64 x){
  union{ unsigned u; float f; } c; c.u = (unsigned)x; return c.f;
}

// 4 f16 MACs: w8/h8 each hold 4 halfs; accumulate into f32.
typedef _Float16 h2_t __attribute__((ext_vector_type(2)));
__device__ __forceinline__ float dot4h(u64 w8, u64 h8, float acc){
#if __has_builtin(__builtin_amdgcn_fdot2)
  union{ u64 x; h2_t v[2]; } cw, ch;
  cw.x = w8; ch.x = h8;
  acc = __builtin_amdgcn_fdot2(cw.v[0], ch.v[0], acc, false);
  acc = __builtin_amdgcn_fdot2(cw.v[1], ch.v[1], acc, false);
#else
  union{ u64 x; __half2 v[2]; } cw, ch;
  cw.x = w8; ch.x = h8;
  float2 a0=__half22float2(cw.v[0]), b0=__half22float2(ch.v[0]);
  float2 a1=__half22float2(cw.v[1]), b1=__half22float2(ch.v[1]);
  acc += a0.x*b0.x + a0.y*b0.y + a1.x*b1.x + a1.y*b1.y;
#endif
  return acc;
}

// sc0 load: bypass L1, read the (shared, same-XCD) L2 copy.
__device__ __forceinline__ u64 ld_sc0(const u64* p){
  u64 x;
  asm volatile("global_load_dwordx2 %0, %1, off sc0\n\ts_waitcnt vmcnt(0)"
               : "=&v"(x) : "v"(p) : "memory");
  return x;
}
// sc0 store: write-through into the shared L2 (visible to same-XCD sc0 loads).
__device__ __forceinline__ void st_sc0(u64* p, u64 v){
  asm volatile("global_store_dwordx2 %0, %1, off sc0" :: "v"(p), "v"(v) : "memory");
}

// Lean 1-RTT poison-detect poll: hot sc0 spin (self-throttled ~250cy by the
// serialized vmcnt(0) L2 round-trip). MALL fallback + sleep only on the
// i>32 slow path — never interleaved into the fast cadence (r17 lesson:
// a 900cy MALL ald inside the loop delays detection of arrived L2 data).
__device__ __forceinline__ u64 poll_fast(const u64* fast, const u64* slow, int lane){
  const u64* pf = fast + lane;
  const u64* ps = slow + lane;
  u64 x = 0;
  for (int i = 0; i < BAIL; ++i){
    x = ld_sc0(pf);
    if (__all(x != POISON64)) return x;
    if (i > 32){
      if ((i & 15) == 0){
        x = ald(ps);
        if (__all(x != POISON64)) return x;
      }
      __builtin_amdgcn_s_sleep(1);
    }
  }
  return x;
}

// deposit u64 entry j=lane (comps 4j..4j+3) into padded h array
// (u64 chunk q at q*17: entry j -> (j>>4)*17 + (j&15)).
__device__ __forceinline__ void deposit64(u64* h8, int lane, u64 x){
  h8[(lane>>4)*17 + (lane&15)] = x;
}

__global__ __launch_bounds__(BT) void fused_kernel(
    const float* __restrict__ v0, const float* __restrict__ m0,
    const float* __restrict__ W1v, const float* __restrict__ b1v,
    const float* __restrict__ W1m, const float* __restrict__ b1m,
    const float* __restrict__ Wih_low, const float* __restrict__ Whh_low,
    const float* __restrict__ bih_low, const float* __restrict__ bhh_low,
    const float* __restrict__ Wih_high, const float* __restrict__ Whh_high,
    const float* __restrict__ bih_high, const float* __restrict__ bhh_high,
    const float* __restrict__ W2v, const float* __restrict__ b2v,
    const float* __restrict__ W2m, const float* __restrict__ b2m,
    float* __restrict__ out,
    u64* h1x, u64* h2x, u64* h1f, u64* h2f, u64* gxt, unsigned* ectl)
{
  // weights: 4 mats x 24 rows; row = 4 chunks of 16 u64 padded to 17 -> 68.
  __shared__ u64 wlds8[96*68];                  // 52224 B
  __shared__ u64 h1u8[68], h2u8[68];            // padded h (f16), 544 B each
  __shared__ float giA_l[24], ghA_l[24], giB_l[24], ghB_l[24];
  __shared__ float gx_lds[48];                  // [par][24]
  __shared__ float xbuf[H];
  __shared__ int s_role, s_idx;

  const int tid = threadIdx.x;
  const int wv = tid >> 6, lane = tid & 63;

  // ---------------- election: find one XCD with >=32 blocks (pigeonhole) ----
  if (tid == 0){
    unsigned xcd;
    asm volatile("s_getreg_b32 %0, hwreg(HW_REG_XCC_ID, 0, 32)" : "=s"(xcd));
    xcd &= 7u;
    unsigned tk = atomicAdd(&ectl[xcd], 1u);
    if (tk == 31u) atomicCAS(&ectl[8], 0u, xcd + 1u);
    unsigned ch; int guard = 0;
    while (!(ch = ald32(&ectl[8]))){
      __builtin_amdgcn_s_sleep(2);
      if (++guard > BAIL){ ch = 1u; break; }
    }
    if (xcd == ch - 1u && tk < 32u){ s_role = 0; s_idx = (int)tk; }
    else {
      unsigned ak = atomicAdd(&ectl[9], 1u);
      if      (ak < 50u ){ s_role = 1; s_idx = (int)ak; }
      else if (ak < 100u){ s_role = 2; s_idx = (int)(ak - 50u); }
      else               { s_role = 3; s_idx = 0; }
    }
  }
  __syncthreads();
  const int role = s_role, idx = s_idx;
  if (role == 3) return;

  if (role == 0){
    // ================================================== scan role
    const int b = idx;
    // stage weights: m: 0=Wih_low[:,256:512] 1=Whh_low 2=Wih_high 3=Whh_high
    for (int i = tid; i < 96*64; i += BT){
      int gr = i >> 6, c = i & 63;
      int m = gr / 24, lr = gr - m*24;
      int gate = lr >> 3, j = lr & 7;
      int row = gate*H + b*HJ + j;
      int k = c*4;
      float4 f;
      if      (m == 0) f = *(const float4*)(Wih_low  + (size_t)row*512 + 256 + k);
      else if (m == 1) f = *(const float4*)(Whh_low  + (size_t)row*256 + k);
      else if (m == 2) f = *(const float4*)(Wih_high + (size_t)row*256 + k);
      else             f = *(const float4*)(Whh_high + (size_t)row*256 + k);
      union{ u64 x; __half2 v[2]; } pk;
      pk.v[0] = __floats2half2_rn(f.x, f.y);
      pk.v[1] = __floats2half2_rn(f.z, f.w);
      wlds8[gr*68 + (c>>4)*17 + (c&15)] = pk.x;
    }
    if (tid < 24){ giA_l[tid]=0.f; ghA_l[tid]=0.f; giB_l[tid]=0.f; ghB_l[tid]=0.f; }

    float hv1 = 0.f, hv2 = 0.f;
    float blR=0,blZ=0,blN=0, biR=0,biZ=0,biN=0, bhR=0,bhZ=0,bhN=0;
    const int jg = b*HJ + lane;               // valid for lane<HJ
    if (wv == 0 && lane < HJ){
      blR = bhh_low [jg]; blZ = bhh_low [H+jg]; blN = bhh_low [2*H+jg];
      biR = bih_high[jg]; biZ = bih_high[H+jg]; biN = bih_high[2*H+jg];
      bhR = bhh_high[jg]; bhZ = bhh_high[H+jg]; bhN = bhh_high[2*H+jg];
      const u64* g = gxt + jg;                // Gx[0] -> gx_lds[0..23]
      int guard = 0;
      while (true){
        u64 a0 = ald(g), a1 = ald(g + H), a2 = ald(g + 2*H);
        bool ok = (((unsigned)(a0>>32))==1u) & (((unsigned)(a1>>32))==1u) & (((unsigned)(a2>>32))==1u);
        if (ok | (++guard > BAIL)){
          gx_lds[lane] = unpackv(a0); gx_lds[8+lane] = unpackv(a1); gx_lds[16+lane] = unpackv(a2);
          break;
        }
        __builtin_amdgcn_s_sleep(4);
      }
    }
    __syncthreads();

    const int gr = wv*16 + (lane >> 2);       // P-phase row (waves 0-2)
    const int q  = lane & 3;

    for (int t = 0; t < T_STEPS; ++t){
      const int par = t & 1;

      // ---- seg_a: wave0 finalize A + dual publish | wave1 Gx[t+1] | wave3 poll h1
      if (wv == 0){
        float hnew = hv1;
        if (lane < HJ){
          float giR = giA_l[lane]    + gx_lds[par*24 + lane];
          float giZ = giA_l[8+lane]  + gx_lds[par*24 + 8 + lane];
          float giN = giA_l[16+lane] + gx_lds[par*24 + 16 + lane];
          float ghR = ghA_l[lane]    + blR;
          float ghZ = ghA_l[8+lane]  + blZ;
          float ghN = ghA_l[16+lane] + blN;
          float r = sigm(giR + ghR), z = sigm(giZ + ghZ);
          float n = ftanh(giN + r * ghN);
          hv1 = (1.f - z) * n + z * hv1;
          hnew = hv1;
        }
        float pa = __shfl(hnew, 4*lane);
        float pb = __shfl(hnew, 4*lane + 1);
        float pc = __shfl(hnew, 4*lane + 2);
        float pd = __shfl(hnew, 4*lane + 3);
        if (lane < 2){
          union{ u64 x; __half2 v[2]; } pk;
          pk.v[0] = __floats2half2_rn(pa, pb);
          pk.v[1] = __floats2half2_rn(pc, pd);
          st_sc0(h1f + (size_t)t*64 + (b<<1) + lane, pk.x);   // fast: XCD L2
          ast  (h1x + (size_t)t*64 + (b<<1) + lane, pk.x);    // slow: MALL (posts + fallback)
        }
      } else if (wv == 1){
        if (lane < HJ && t + 1 < T_STEPS){               // prefetch Gx[t+1]
          const u64* g = gxt + (size_t)(t+1)*G3 + jg;
          int guard = 0;
          while (true){
            u64 a0 = ald(g), a1 = ald(g + H), a2 = ald(g + 2*H);
            bool ok = (((unsigned)(a0>>32))==1u) & (((unsigned)(a1>>32))==1u) & (((unsigned)(a2>>32))==1u);
            if (ok | (++guard > BAIL)){
              int np = (1 - par) * 24;
              gx_lds[np + lane] = unpackv(a0); gx_lds[np + 8 + lane] = unpackv(a1); gx_lds[np + 16 + lane] = unpackv(a2);
              break;
            }
            __builtin_amdgcn_s_sleep(1);
          }
        }
      }
      if (t == T_STEPS - 1) break;
      if (wv == 3){
        u64 px = poll_fast(h1f + (size_t)t*64, h1x + (size_t)t*64, lane);
        deposit64(h1u8, lane, px);
      }
      __syncthreads();                                   // bar1: h1 ready

      // ---- P1: 48 rows on h1: gi_B (mat2) rows 0..23, gh_A' (mat1) rows 24..47
      if (wv < 3){
        int wr = (gr < 24) ? (48 + gr) : gr;             // mat2 base 48, mat1 base 24
        const u64* wrow = wlds8 + wr*68 + q*17;
        const u64* hh = h1u8 + q*17;
        float s = 0.f;
        #pragma unroll
        for (int i = 0; i < 16; ++i) s = dot4h(wrow[i], hh[i], s);
        s += __shfl_xor(s, 1);
        s += __shfl_xor(s, 2);
        if (q == 0){ if (gr < 24) giB_l[gr] = s; else ghA_l[gr-24] = s; }
      }
      __syncthreads();                                   // bar2: gi_B/gh_A' ready

      // ---- seg_b: wave0 finalize B + dual publish | wave3 poll h2
      if (wv == 0){
        float hnew = hv2;
        if (lane < HJ){
          float giR = giB_l[lane]    + biR, ghR = ghB_l[lane]    + bhR;
          float giZ = giB_l[8+lane]  + biZ, ghZ = ghB_l[8+lane]  + bhZ;
          float giN = giB_l[16+lane] + biN, ghN = ghB_l[16+lane] + bhN;
          float r = sigm(giR + ghR), z = sigm(giZ + ghZ);
          float n = ftanh(giN + r * ghN);
          hv2 = (1.f - z) * n + z * hv2;
          hnew = hv2;
        }
        float pa = __shfl(hnew, 4*lane);
        float pb = __shfl(hnew, 4*lane + 1);
        float pc = __shfl(hnew, 4*lane + 2);
        float pd = __shfl(hnew, 4*lane + 3);
        if (lane < 2){
          union{ u64 x; __half2 v[2]; } pk;
          pk.v[0] = __floats2half2_rn(pa, pb);
          pk.v[1] = __floats2half2_rn(pc, pd);
          st_sc0(h2f + (size_t)t*64 + (b<<1) + lane, pk.x);   // fast: XCD L2
          ast  (h2x + (size_t)t*64 + (b<<1) + lane, pk.x);    // slow: fallback
        }
      } else if (wv == 3){
        u64 py = poll_fast(h2f + (size_t)t*64, h2x + (size_t)t*64, lane);
        deposit64(h2u8, lane, py);
      }
      __syncthreads();                                   // bar3: h2 ready

      // ---- P2: 48 rows on h2: gi_A' (mat0) rows 0..23, gh_B' (mat3) rows 24..47
      if (wv < 3){
        int wr = (gr < 24) ? gr : (48 + gr);             // mat0 base 0, mat3 base 72
        const u64* wrow = wlds8 + wr*68 + q*17;
        const u64* hh = h2u8 + q*17;
        float s = 0.f;
        #pragma unroll
        for (int i = 0; i < 16; ++i) s = dot4h(wrow[i], hh[i], s);
        s += __shfl_xor(s, 1);
        s += __shfl_xor(s, 2);
        if (q == 0){ if (gr < 24) giA_l[gr] = s; else ghB_l[gr-24] = s; }
      }
      __syncthreads();                                   // bar4
    }

  } else if (role == 1){
    // ================================================== featgx role
    const int t = idx;
    { int j = tid >> 1, s = tid & 1;
      const float4* a4 = reinterpret_cast<const float4*>(v0 + (size_t)t*VIN) + s*96;
      const float4* w4 = reinterpret_cast<const float4*>(W1v + (size_t)j*VIN) + s*96;
      float p = 0.f;
      #pragma unroll 4
      for (int c = 0; c < 96; ++c){
        float4 a = a4[c], w = w4[c];
        p += a.x*w.x + a.y*w.y + a.z*w.z + a.w*w.w;
      }
      p += __shfl_xor(p, 1);
      if (s == 0) xbuf[j] = eluf(p + b1v[j]);
    }
    if (tid < VF){
      float am = b1m[tid] + W1m[tid*2]*m0[t*2] + W1m[tid*2+1]*m0[t*2+1];
      xbuf[VF + tid] = eluf(am);
    }
    __syncthreads();
    #pragma unroll
    for (int k = 0; k < 3; ++k){
      int r = k*256 + tid;
      const float4* w4 = reinterpret_cast<const float4*>(Wih_low + (size_t)r*(2*H));
      const float4* x4 = reinterpret_cast<const float4*>(xbuf);
      float acc = bih_low[r];
      #pragma unroll 8
      for (int c = 0; c < 64; ++c){
        float4 w = w4[c], x = x4[c];
        acc += w.x*x.x + w.y*x.y + w.z*x.z + w.w*x.w;
      }
      ast(gxt + (size_t)t*G3 + r, packtv(1u, acc));
    }

  } else {
    // ================================================== post role
    const int t = idx;
    for (int i = 0; i < t; ++i) __builtin_amdgcn_s_sleep(32);   // staggered start
    if (wv == 0){
      // poison-poll h1x[t] (MALL copy ONLY — a remote L2 would cache the
      // poison line and never see the scan XCD's update: cross-XCD trap).
      const u64* p = h1x + (size_t)t*64 + lane;
      u64 x = 0; int guard = 0;
      while (true){
        x = ald(p);
        if (__all(x != POISON64) | (++guard > BAIL)) break;
        __builtin_amdgcn_s_sleep(8);
      }
      union{ u64 v; __half2 h[2]; } c; c.v = x;
      float2 f0 = __half22float2(c.h[0]);
      float2 f1 = __half22float2(c.h[1]);
      xbuf[4*lane    ] = eluf(f0.x);
      xbuf[4*lane + 1] = eluf(f0.y);
      xbuf[4*lane + 2] = eluf(f1.x);
      xbuf[4*lane + 3] = eluf(f1.y);
    }
    __syncthreads();
    #pragma unroll
    for (int k = 0; k < 3; ++k){
      int r = k*256 + tid;
      const float4* w4 = reinterpret_cast<const float4*>(W2v + (size_t)r*VF);
      const float4* f4 = reinterpret_cast<const float4*>(xbuf);
      float acc = b2v[r];
      #pragma unroll 8
      for (int c = 0; c < 32; ++c){
        float4 w = w4[c], x = f4[c];
        acc += w.x*x.x + w.y*x.y + w.z*x.z + w.w*x.w;
      }
      out[(size_t)t*VIN + r] = sigm(acc);
    }
    if (tid < MIN_){
      const float* wm = W2m + tid*VF;
      float am = b2m[tid];
      #pragma unroll 8
      for (int c = 0; c < VF; ++c) am += wm[c] * xbuf[VF + c];
      out[(size_t)T_STEPS*VIN + t*MIN_ + tid] = tanhf(am);
    }
  }
}

extern "C" void kernel_launch(void* const* d_in, const int* in_sizes, int n_in,
                              void* d_out, int out_size, void* d_ws, size_t ws_size,
                              hipStream_t stream)
{
  const float* v0       = (const float*)d_in[0];
  const float* m0       = (const float*)d_in[1];
  const float* W1v      = (const float*)d_in[2];
  const float* b1v      = (const float*)d_in[3];
  const float* W1m      = (const float*)d_in[4];
  const float* b1m      = (const float*)d_in[5];
  const float* Wih_low  = (const float*)d_in[6];
  const float* Whh_low  = (const float*)d_in[7];
  const float* bih_low  = (const float*)d_in[8];
  const float* bhh_low  = (const float*)d_in[9];
  const float* Wih_high = (const float*)d_in[10];
  const float* Whh_high = (const float*)d_in[11];
  const float* bih_high = (const float*)d_in[12];
  const float* bhh_high = (const float*)d_in[13];
  const float* W2v      = (const float*)d_in[14];
  const float* b2v      = (const float*)d_in[15];
  const float* W2m      = (const float*)d_in[16];
  const float* b2m      = (const float*)d_in[17];
  float* out = (float*)d_out;

  // ws layout (8B-aligned).
  // h1x/h2x: [50][64] u64 MALL exchange buffers (agent-scope; posts+fallback).
  // h1f/h2f: [50][64] u64 FAST exchange buffers (same-XCD L2 via sc0).
  // All four poisoned 0xFF per launch (0xFFFF halfs = NaN, unreachable).
  // gxt: tagged (tag=1). Total ~410 KB (< proven 414 KB budget).
  char* ws = (char*)d_ws;
  u64* h1x      = (u64*)(ws + 0);               // 25600 B
  u64* h2x      = (u64*)(ws + 25600);           // 25600 B
  u64* h1f      = (u64*)(ws + 51200);           // 25600 B
  u64* h2f      = (u64*)(ws + 76800);           // 25600 B (ends 102400)
  u64* gxt      = (u64*)(ws + 102400);          // 307200 B (ends 409600)
  unsigned* ectl= (unsigned*)(ws + 409600);     // election state

  hipMemsetAsync(ws, 0xFF, 102400, stream);     // poison all exchange buffers
  hipMemsetAsync(ws + 409600, 0, 256, stream);  // zero election state

  fused_kernel<<<NBLOCKS, BT, 0, stream>>>(
      v0, m0, W1v, b1v, W1m, b1m,
      Wih_low, Whh_low, bih_low, bhh_low,
      Wih_high, Whh_high, bih_high, bhh_high,
      W2v, b2v, W2m, b2m, out,
      h1x, h2x, h1f, h2f, gxt, ectl);
}

// Round 7
// 312.032 us; speedup vs baseline: 2.3165x; 2.3165x over previous
//
#include <hip/hip_runtime.h>
#include <hip/hip_fp16.h>

// Stacked GRU (T=50, B=1, H=256) on MI355X — round 19.
// r17 skeleton, ONE instruction changed: fast-path publish is now an
// L2-SCOPE ATOMIC SWAP (global_atomic_swap_x2, no sc bits).
//  - r18 post-mortem proved sc0 STORES write AROUND the XCD L2 (no-allocate
//    -> pollers' L2 caches poison forever; r17's detection was secretly the
//    every-4th MALL ald). Plain atomics EXECUTE AT the local L2 and
//    update/allocate the line there (r12 proved correctness of swap-publish)
//    -> the poller's sc0 load now L2-hits the swap-dirtied line (~250cy).
//  - poll identical to r17 (sc0 every iter, MALL every 4th, sleep i>16):
//    if the swap path is live we exit in ~2 iters; if dead we degrade to
//    exactly r17's proven 198us behavior. Single-variable experiment.
//  - MALL copy (ast) still dual-published for post blocks + fallback.
// r13 lesson: detection rides WITH data — kept. r12: no RMW POLLS — kept
// (one swap per publisher is fine; it was the 4096-RMW poll storm that hurt).
// r15/r18 lesson: MALL poll cadence gentle, never demoted too far — kept.

#define T_STEPS 50
#define VIN 768
#define VF 128
#define MIN_ 2
#define H 256
#define G3 768

#define NB 32
#define BT 256
#define HJ 8
#define BAIL 4000000
#define NBLOCKS 264

typedef unsigned long long u64;
#define POISON64 0xFFFFFFFFFFFFFFFFull

__device__ __forceinline__ float sigm(float x){
  x = fminf(fmaxf(x, -30.f), 30.f);
  return __builtin_amdgcn_rcpf(1.f + __expf(-x));
}
__device__ __forceinline__ float ftanh(float x){
  x = fminf(fmaxf(x, -9.f), 9.f);
  float e = __expf(2.f*x);
  return (e - 1.f) * __builtin_amdgcn_rcpf(e + 1.f);
}
__device__ __forceinline__ float eluf(float x){ return x > 0.0f ? x : expm1f(x); }

__device__ __forceinline__ u64 ald(const u64* p){
  return __hip_atomic_load(const_cast<u64*>(p), __ATOMIC_RELAXED, __HIP_MEMORY_SCOPE_AGENT);
}
__device__ __forceinline__ unsigned ald32(const unsigned* p){
  return __hip_atomic_load(const_cast<unsigned*>(p), __ATOMIC_RELAXED, __HIP_MEMORY_SCOPE_AGENT);
}
__device__ __forceinline__ void ast(u64* p, u64 v){
  __hip_atomic_store(p, v, __ATOMIC_RELAXED, __HIP_MEMORY_SCOPE_AGENT);
}
__device__ __forceinline__ u64 packtv(unsigned tag, float v){
  union{ float f; unsigned u; } c; c.f = v;
  return ((u64)tag << 32) | (u64)c.u;
}
__device__ __forceinline__ float unpackv(u64 x){
  union{ unsigned u; float f; } c; c.u = (unsigned)x; return c.f;
}

// 4 f16 MACs: w8/h8 each hold 4 halfs; accumulate into f32.
typedef _Float16 h2_t __attribute__((ext_vector_type(2)));
__device__ __forceinline__ float dot4h(u64 w8, u64 h8, float acc){
#if __has_builtin(__builtin_amdgcn_fdot2)
  union{ u64 x; h2_t v[2]; } cw, ch;
  cw.x = w8; ch.x = h8;
  acc = __builtin_amdgcn_fdot2(cw.v[0], ch.v[0], acc, false);
  acc = __builtin_amdgcn_fdot2(cw.v[1], ch.v[1], acc, false);
#else
  union{ u64 x; __half2 v[2]; } cw, ch;
  cw.x = w8; ch.x = h8;
  float2 a0=__half22float2(cw.v[0]), b0=__half22float2(ch.v[0]);
  float2 a1=__half22float2(cw.v[1]), b1=__half22float2(ch.v[1]);
  acc += a0.x*b0.x + a0.y*b0.y + a1.x*b1.x + a1.y*b1.y;
#endif
  return acc;
}

// sc0 load: bypass L1, look up the (shared, same-XCD) L2 copy.
__device__ __forceinline__ u64 ld_sc0(const u64* p){
  u64 x;
  asm volatile("global_load_dwordx2 %0, %1, off sc0\n\ts_waitcnt vmcnt(0)"
               : "=&v"(x) : "v"(p) : "memory");
  return x;
}
// L2-scope atomic swap publish (no sc bits -> executes AT the local XCD L2,
// updating/allocating the line there; no return value). r12-proven correct.
__device__ __forceinline__ void swap_l2(u64* p, u64 v){
  asm volatile("global_atomic_swap_x2 %0, %1, off" :: "v"(p), "v"(v) : "memory");
}

// Dual-path 1-RTT poison-detect poll (r17 cadence, unchanged): fast sc0 L2
// lookup every iter; MALL fallback every 4th iter; sleep after 16. If the
// L2-swap publish is live we exit within ~2 iters; else this IS r17.
__device__ __forceinline__ u64 poll_dual(const u64* fast, const u64* slow, int lane){
  const u64* pf = fast + lane;
  const u64* ps = slow + lane;
  u64 x = 0;
  for (int i = 0; i < BAIL; ++i){
    x = ld_sc0(pf);
    if (__all(x != POISON64)) return x;
    if ((i & 3) == 3){
      x = ald(ps);
      if (__all(x != POISON64)) return x;
    }
    if (i > 16) __builtin_amdgcn_s_sleep(1);
  }
  return x;
}

// deposit u64 entry j=lane (comps 4j..4j+3) into padded h array
// (u64 chunk q at q*17: entry j -> (j>>4)*17 + (j&15)).
__device__ __forceinline__ void deposit64(u64* h8, int lane, u64 x){
  h8[(lane>>4)*17 + (lane&15)] = x;
}

__global__ __launch_bounds__(BT) void fused_kernel(
    const float* __restrict__ v0, const float* __restrict__ m0,
    const float* __restrict__ W1v, const float* __restrict__ b1v,
    const float* __restrict__ W1m, const float* __restrict__ b1m,
    const float* __restrict__ Wih_low, const float* __restrict__ Whh_low,
    const float* __restrict__ bih_low, const float* __restrict__ bhh_low,
    const float* __restrict__ Wih_high, const float* __restrict__ Whh_high,
    const float* __restrict__ bih_high, const float* __restrict__ bhh_high,
    const float* __restrict__ W2v, const float* __restrict__ b2v,
    const float* __restrict__ W2m, const float* __restrict__ b2m,
    float* __restrict__ out,
    u64* h1x, u64* h2x, u64* h1f, u64* h2f, u64* gxt, unsigned* ectl)
{
  // weights: 4 mats x 24 rows; row = 4 chunks of 16 u64 padded to 17 -> 68.
  __shared__ u64 wlds8[96*68];                  // 52224 B
  __shared__ u64 h1u8[68], h2u8[68];            // padded h (f16), 544 B each
  __shared__ float giA_l[24], ghA_l[24], giB_l[24], ghB_l[24];
  __shared__ float gx_lds[48];                  // [par][24]
  __shared__ float xbuf[H];
  __shared__ int s_role, s_idx;

  const int tid = threadIdx.x;
  const int wv = tid >> 6, lane = tid & 63;

  // ---------------- election: find one XCD with >=32 blocks (pigeonhole) ----
  if (tid == 0){
    unsigned xcd;
    asm volatile("s_getreg_b32 %0, hwreg(HW_REG_XCC_ID, 0, 32)" : "=s"(xcd));
    xcd &= 7u;
    unsigned tk = atomicAdd(&ectl[xcd], 1u);
    if (tk == 31u) atomicCAS(&ectl[8], 0u, xcd + 1u);
    unsigned ch; int guard = 0;
    while (!(ch = ald32(&ectl[8]))){
      __builtin_amdgcn_s_sleep(2);
      if (++guard > BAIL){ ch = 1u; break; }
    }
    if (xcd == ch - 1u && tk < 32u){ s_role = 0; s_idx = (int)tk; }
    else {
      unsigned ak = atomicAdd(&ectl[9], 1u);
      if      (ak < 50u ){ s_role = 1; s_idx = (int)ak; }
      else if (ak < 100u){ s_role = 2; s_idx = (int)(ak - 50u); }
      else               { s_role = 3; s_idx = 0; }
    }
  }
  __syncthreads();
  const int role = s_role, idx = s_idx;
  if (role == 3) return;

  if (role == 0){
    // ================================================== scan role
    const int b = idx;
    // stage weights: m: 0=Wih_low[:,256:512] 1=Whh_low 2=Wih_high 3=Whh_high
    for (int i = tid; i < 96*64; i += BT){
      int gr = i >> 6, c = i & 63;
      int m = gr / 24, lr = gr - m*24;
      int gate = lr >> 3, j = lr & 7;
      int row = gate*H + b*HJ + j;
      int k = c*4;
      float4 f;
      if      (m == 0) f = *(const float4*)(Wih_low  + (size_t)row*512 + 256 + k);
      else if (m == 1) f = *(const float4*)(Whh_low  + (size_t)row*256 + k);
      else if (m == 2) f = *(const float4*)(Wih_high + (size_t)row*256 + k);
      else             f = *(const float4*)(Whh_high + (size_t)row*256 + k);
      union{ u64 x; __half2 v[2]; } pk;
      pk.v[0] = __floats2half2_rn(f.x, f.y);
      pk.v[1] = __floats2half2_rn(f.z, f.w);
      wlds8[gr*68 + (c>>4)*17 + (c&15)] = pk.x;
    }
    if (tid < 24){ giA_l[tid]=0.f; ghA_l[tid]=0.f; giB_l[tid]=0.f; ghB_l[tid]=0.f; }

    float hv1 = 0.f, hv2 = 0.f;
    float blR=0,blZ=0,blN=0, biR=0,biZ=0,biN=0, bhR=0,bhZ=0,bhN=0;
    const int jg = b*HJ + lane;               // valid for lane<HJ
    if (wv == 0 && lane < HJ){
      blR = bhh_low [jg]; blZ = bhh_low [H+jg]; blN = bhh_low [2*H+jg];
      biR = bih_high[jg]; biZ = bih_high[H+jg]; biN = bih_high[2*H+jg];
      bhR = bhh_high[jg]; bhZ = bhh_high[H+jg]; bhN = bhh_high[2*H+jg];
      const u64* g = gxt + jg;                // Gx[0] -> gx_lds[0..23]
      int guard = 0;
      while (true){
        u64 a0 = ald(g), a1 = ald(g + H), a2 = ald(g + 2*H);
        bool ok = (((unsigned)(a0>>32))==1u) & (((unsigned)(a1>>32))==1u) & (((unsigned)(a2>>32))==1u);
        if (ok | (++guard > BAIL)){
          gx_lds[lane] = unpackv(a0); gx_lds[8+lane] = unpackv(a1); gx_lds[16+lane] = unpackv(a2);
          break;
        }
        __builtin_amdgcn_s_sleep(4);
      }
    }
    __syncthreads();

    const int gr = wv*16 + (lane >> 2);       // P-phase row (waves 0-2)
    const int q  = lane & 3;

    for (int t = 0; t < T_STEPS; ++t){
      const int par = t & 1;

      // ---- seg_a: wave0 finalize A + dual publish | wave1 Gx[t+1] | wave3 poll h1
      if (wv == 0){
        float hnew = hv1;
        if (lane < HJ){
          float giR = giA_l[lane]    + gx_lds[par*24 + lane];
          float giZ = giA_l[8+lane]  + gx_lds[par*24 + 8 + lane];
          float giN = giA_l[16+lane] + gx_lds[par*24 + 16 + lane];
          float ghR = ghA_l[lane]    + blR;
          float ghZ = ghA_l[8+lane]  + blZ;
          float ghN = ghA_l[16+lane] + blN;
          float r = sigm(giR + ghR), z = sigm(giZ + ghZ);
          float n = ftanh(giN + r * ghN);
          hv1 = (1.f - z) * n + z * hv1;
          hnew = hv1;
        }
        float pa = __shfl(hnew, 4*lane);
        float pb = __shfl(hnew, 4*lane + 1);
        float pc = __shfl(hnew, 4*lane + 2);
        float pd = __shfl(hnew, 4*lane + 3);
        if (lane < 2){
          union{ u64 x; __half2 v[2]; } pk;
          pk.v[0] = __floats2half2_rn(pa, pb);
          pk.v[1] = __floats2half2_rn(pc, pd);
          swap_l2(h1f + (size_t)t*64 + (b<<1) + lane, pk.x);  // fast: L2-scope atomic
          ast  (h1x + (size_t)t*64 + (b<<1) + lane, pk.x);    // slow: MALL (posts + fallback)
        }
      } else if (wv == 1){
        if (lane < HJ && t + 1 < T_STEPS){               // prefetch Gx[t+1]
          const u64* g = gxt + (size_t)(t+1)*G3 + jg;
          int guard = 0;
          while (true){
            u64 a0 = ald(g), a1 = ald(g + H), a2 = ald(g + 2*H);
            bool ok = (((unsigned)(a0>>32))==1u) & (((unsigned)(a1>>32))==1u) & (((unsigned)(a2>>32))==1u);
            if (ok | (++guard > BAIL)){
              int np = (1 - par) * 24;
              gx_lds[np + lane] = unpackv(a0); gx_lds[np + 8 + lane] = unpackv(a1); gx_lds[np + 16 + lane] = unpackv(a2);
              break;
            }
            __builtin_amdgcn_s_sleep(1);
          }
        }
      }
      if (t == T_STEPS - 1) break;
      if (wv == 3){
        u64 px = poll_dual(h1f + (size_t)t*64, h1x + (size_t)t*64, lane);
        deposit64(h1u8, lane, px);
      }
      __syncthreads();                                   // bar1: h1 ready

      // ---- P1: 48 rows on h1: gi_B (mat2) rows 0..23, gh_A' (mat1) rows 24..47
      if (wv < 3){
        int wr = (gr < 24) ? (48 + gr) : gr;             // mat2 base 48, mat1 base 24
        const u64* wrow = wlds8 + wr*68 + q*17;
        const u64* hh = h1u8 + q*17;
        float s = 0.f;
        #pragma unroll
        for (int i = 0; i < 16; ++i) s = dot4h(wrow[i], hh[i], s);
        s += __shfl_xor(s, 1);
        s += __shfl_xor(s, 2);
        if (q == 0){ if (gr < 24) giB_l[gr] = s; else ghA_l[gr-24] = s; }
      }
      __syncthreads();                                   // bar2: gi_B/gh_A' ready

      // ---- seg_b: wave0 finalize B + dual publish | wave3 poll h2
      if (wv == 0){
        float hnew = hv2;
        if (lane < HJ){
          float giR = giB_l[lane]    + biR, ghR = ghB_l[lane]    + bhR;
          float giZ = giB_l[8+lane]  + biZ, ghZ = ghB_l[8+lane]  + bhZ;
          float giN = giB_l[16+lane] + biN, ghN = ghB_l[16+lane] + bhN;
          float r = sigm(giR + ghR), z = sigm(giZ + ghZ);
          float n = ftanh(giN + r * ghN);
          hv2 = (1.f - z) * n + z * hv2;
          hnew = hv2;
        }
        float pa = __shfl(hnew, 4*lane);
        float pb = __shfl(hnew, 4*lane + 1);
        float pc = __shfl(hnew, 4*lane + 2);
        float pd = __shfl(hnew, 4*lane + 3);
        if (lane < 2){
          union{ u64 x; __half2 v[2]; } pk;
          pk.v[0] = __floats2half2_rn(pa, pb);
          pk.v[1] = __floats2half2_rn(pc, pd);
          swap_l2(h2f + (size_t)t*64 + (b<<1) + lane, pk.x);  // fast: L2-scope atomic
          ast  (h2x + (size_t)t*64 + (b<<1) + lane, pk.x);    // slow: fallback
        }
      } else if (wv == 3){
        u64 py = poll_dual(h2f + (size_t)t*64, h2x + (size_t)t*64, lane);
        deposit64(h2u8, lane, py);
      }
      __syncthreads();                                   // bar3: h2 ready

      // ---- P2: 48 rows on h2: gi_A' (mat0) rows 0..23, gh_B' (mat3) rows 24..47
      if (wv < 3){
        int wr = (gr < 24) ? gr : (48 + gr);             // mat0 base 0, mat3 base 72
        const u64* wrow = wlds8 + wr*68 + q*17;
        const u64* hh = h2u8 + q*17;
        float s = 0.f;
        #pragma unroll
        for (int i = 0; i < 16; ++i) s = dot4h(wrow[i], hh[i], s);
        s += __shfl_xor(s, 1);
        s += __shfl_xor(s, 2);
        if (q == 0){ if (gr < 24) giA_l[gr] = s; else ghB_l[gr-24] = s; }
      }
      __syncthreads();                                   // bar4
    }

  } else if (role == 1){
    // ================================================== featgx role
    const int t = idx;
    { int j = tid >> 1, s = tid & 1;
      const float4* a4 = reinterpret_cast<const float4*>(v0 + (size_t)t*VIN) + s*96;
      const float4* w4 = reinterpret_cast<const float4*>(W1v + (size_t)j*VIN) + s*96;
      float p = 0.f;
      #pragma unroll 4
      for (int c = 0; c < 96; ++c){
        float4 a = a4[c], w = w4[c];
        p += a.x*w.x + a.y*w.y + a.z*w.z + a.w*w.w;
      }
      p += __shfl_xor(p, 1);
      if (s == 0) xbuf[j] = eluf(p + b1v[j]);
    }
    if (tid < VF){
      float am = b1m[tid] + W1m[tid*2]*m0[t*2] + W1m[tid*2+1]*m0[t*2+1];
      xbuf[VF + tid] = eluf(am);
    }
    __syncthreads();
    #pragma unroll
    for (int k = 0; k < 3; ++k){
      int r = k*256 + tid;
      const float4* w4 = reinterpret_cast<const float4*>(Wih_low + (size_t)r*(2*H));
      const float4* x4 = reinterpret_cast<const float4*>(xbuf);
      float acc = bih_low[r];
      #pragma unroll 8
      for (int c = 0; c < 64; ++c){
        float4 w = w4[c], x = x4[c];
        acc += w.x*x.x + w.y*x.y + w.z*x.z + w.w*x.w;
      }
      ast(gxt + (size_t)t*G3 + r, packtv(1u, acc));
    }

  } else {
    // ================================================== post role
    const int t = idx;
    for (int i = 0; i < t; ++i) __builtin_amdgcn_s_sleep(32);   // staggered start
    if (wv == 0){
      // poison-poll h1x[t] (MALL copy ONLY — a remote L2 would cache the
      // poison line and never see the scan XCD's update: cross-XCD trap).
      const u64* p = h1x + (size_t)t*64 + lane;
      u64 x = 0; int guard = 0;
      while (true){
        x = ald(p);
        if (__all(x != POISON64) | (++guard > BAIL)) break;
        __builtin_amdgcn_s_sleep(8);
      }
      union{ u64 v; __half2 h[2]; } c; c.v = x;
      float2 f0 = __half22float2(c.h[0]);
      float2 f1 = __half22float2(c.h[1]);
      xbuf[4*lane    ] = eluf(f0.x);
      xbuf[4*lane + 1] = eluf(f0.y);
      xbuf[4*lane + 2] = eluf(f1.x);
      xbuf[4*lane + 3] = eluf(f1.y);
    }
    __syncthreads();
    #pragma unroll
    for (int k = 0; k < 3; ++k){
      int r = k*256 + tid;
      const float4* w4 = reinterpret_cast<const float4*>(W2v + (size_t)r*VF);
      const float4* f4 = reinterpret_cast<const float4*>(xbuf);
      float acc = b2v[r];
      #pragma unroll 8
      for (int c = 0; c < 32; ++c){
        float4 w = w4[c], x = f4[c];
        acc += w.x*x.x + w.y*x.y + w.z*x.z + w.w*x.w;
      }
      out[(size_t)t*VIN + r] = sigm(acc);
    }
    if (tid < MIN_){
      const float* wm = W2m + tid*VF;
      float am = b2m[tid];
      #pragma unroll 8
      for (int c = 0; c < VF; ++c) am += wm[c] * xbuf[VF + c];
      out[(size_t)T_STEPS*VIN + t*MIN_ + tid] = tanhf(am);
    }
  }
}

extern "C" void kernel_launch(void* const* d_in, const int* in_sizes, int n_in,
                              void* d_out, int out_size, void* d_ws, size_t ws_size,
                              hipStream_t stream)
{
  const float* v0       = (const float*)d_in[0];
  const float* m0       = (const float*)d_in[1];
  const float* W1v      = (const float*)d_in[2];
  const float* b1v      = (const float*)d_in[3];
  const float* W1m      = (const float*)d_in[4];
  const float* b1m      = (const float*)d_in[5];
  const float* Wih_low  = (const float*)d_in[6];
  const float* Whh_low  = (const float*)d_in[7];
  const float* bih_low  = (const float*)d_in[8];
  const float* bhh_low  = (const float*)d_in[9];
  const float* Wih_high = (const float*)d_in[10];
  const float* Whh_high = (const float*)d_in[11];
  const float* bih_high = (const float*)d_in[12];
  const float* bhh_high = (const float*)d_in[13];
  const float* W2v      = (const float*)d_in[14];
  const float* b2v      = (const float*)d_in[15];
  const float* W2m      = (const float*)d_in[16];
  const float* b2m      = (const float*)d_in[17];
  float* out = (float*)d_out;

  // ws layout (8B-aligned).
  // h1x/h2x: [50][64] u64 MALL exchange buffers (agent-scope; posts+fallback).
  // h1f/h2f: [50][64] u64 FAST exchange buffers (same-XCD L2 via atomic swap).
  // All four poisoned 0xFF per launch (0xFFFF halfs = NaN, unreachable).
  // gxt: tagged (tag=1). Total ~410 KB (< proven 414 KB budget).
  char* ws = (char*)d_ws;
  u64* h1x      = (u64*)(ws + 0);               // 25600 B
  u64* h2x      = (u64*)(ws + 25600);           // 25600 B
  u64* h1f      = (u64*)(ws + 51200);           // 25600 B
  u64* h2f      = (u64*)(ws + 76800);           // 25600 B (ends 102400)
  u64* gxt      = (u64*)(ws + 102400);          // 307200 B (ends 409600)
  unsigned* ectl= (unsigned*)(ws + 409600);     // election state

  hipMemsetAsync(ws, 0xFF, 102400, stream);     // poison all exchange buffers
  hipMemsetAsync(ws + 409600, 0, 256, stream);  // zero election state

  fused_kernel<<<NBLOCKS, BT, 0, stream>>>(
      v0, m0, W1v, b1v, W1m, b1m,
      Wih_low, Whh_low, bih_low, bhh_low,
      Wih_high, Whh_high, bih_high, bhh_high,
      W2v, b2v, W2m, b2m, out,
      h1x, h2x, h1f, h2f, gxt, ectl);
}

// Round 8
// 269.419 us; speedup vs baseline: 2.6829x; 1.1582x over previous
//
#include <hip/hip_runtime.h>
#include <hip/hip_fp16.h>

// Stacked GRU (T=50, B=1, H=256) on MI355X — round 20.
// EXACT r17 revert (proven 198us: sc0-store + MALL-ast dual publish,
// sc0-spaced MALL poll) with ONE cadence change:
//  - MALL ald check every 2ND iter (was every 4th): sampling period
//    ~1500cy -> ~1075cy while keeping one sc0 spacer per check.
// r18/r19 post-mortem (CLOSED ARC): same-XCD L2 exchange is unusable here —
//  sc0 stores bypass L2; atomic swaps don't feed sc0 loads either; ALL
//  detection flows through the agent-scope MALL ald. The sc0 "fast" loads
//  are stale L2 hits that act as cheap spacers only.
// r13 lesson: detection rides WITH data (one transaction) — kept.
// r12 lesson: no RMWs on/near exchange lines — kept.
// r15/r16 lesson: some spacing between MALL sweeps helps; zero or 3x-deep
//  hot polling hurts — hence exactly one spacer per MALL check.

#define T_STEPS 50
#define VIN 768
#define VF 128
#define MIN_ 2
#define H 256
#define G3 768

#define NB 32
#define BT 256
#define HJ 8
#define BAIL 4000000
#define NBLOCKS 264

typedef unsigned long long u64;
#define POISON64 0xFFFFFFFFFFFFFFFFull

__device__ __forceinline__ float sigm(float x){
  x = fminf(fmaxf(x, -30.f), 30.f);
  return __builtin_amdgcn_rcpf(1.f + __expf(-x));
}
__device__ __forceinline__ float ftanh(float x){
  x = fminf(fmaxf(x, -9.f), 9.f);
  float e = __expf(2.f*x);
  return (e - 1.f) * __builtin_amdgcn_rcpf(e + 1.f);
}
__device__ __forceinline__ float eluf(float x){ return x > 0.0f ? x : expm1f(x); }

__device__ __forceinline__ u64 ald(const u64* p){
  return __hip_atomic_load(const_cast<u64*>(p), __ATOMIC_RELAXED, __HIP_MEMORY_SCOPE_AGENT);
}
__device__ __forceinline__ unsigned ald32(const unsigned* p){
  return __hip_atomic_load(const_cast<unsigned*>(p), __ATOMIC_RELAXED, __HIP_MEMORY_SCOPE_AGENT);
}
__device__ __forceinline__ void ast(u64* p, u64 v){
  __hip_atomic_store(p, v, __ATOMIC_RELAXED, __HIP_MEMORY_SCOPE_AGENT);
}
__device__ __forceinline__ u64 packtv(unsigned tag, float v){
  union{ float f; unsigned u; } c; c.f = v;
  return ((u64)tag << 32) | (u64)c.u;
}
__device__ __forceinline__ float unpackv(u64 x){
  union{ unsigned u; float f; } c; c.u = (unsigned)x; return c.f;
}

// 4 f16 MACs: w8/h8 each hold 4 halfs; accumulate into f32.
typedef _Float16 h2_t __attribute__((ext_vector_type(2)));
__device__ __forceinline__ float dot4h(u64 w8, u64 h8, float acc){
#if __has_builtin(__builtin_amdgcn_fdot2)
  union{ u64 x; h2_t v[2]; } cw, ch;
  cw.x = w8; ch.x = h8;
  acc = __builtin_amdgcn_fdot2(cw.v[0], ch.v[0], acc, false);
  acc = __builtin_amdgcn_fdot2(cw.v[1], ch.v[1], acc, false);
#else
  union{ u64 x; __half2 v[2]; } cw, ch;
  cw.x = w8; ch.x = h8;
  float2 a0=__half22float2(cw.v[0]), b0=__half22float2(ch.v[0]);
  float2 a1=__half22float2(cw.v[1]), b1=__half22float2(ch.v[1]);
  acc += a0.x*b0.x + a0.y*b0.y + a1.x*b1.x + a1.y*b1.y;
#endif
  return acc;
}

// sc0 load: stale L2 hit (~150-200cy) — used purely as a cheap spacer.
__device__ __forceinline__ u64 ld_sc0(const u64* p){
  u64 x;
  asm volatile("global_load_dwordx2 %0, %1, off sc0\n\ts_waitcnt vmcnt(0)"
               : "=&v"(x) : "v"(p) : "memory");
  return x;
}
// sc0 store: write-through toward MALL (r17 publish form, proven fastest).
__device__ __forceinline__ void st_sc0(u64* p, u64 v){
  asm volatile("global_store_dwordx2 %0, %1, off sc0" :: "v"(p), "v"(v) : "memory");
}

// Poison-detect poll: one sc0 spacer + MALL ald every 2nd iter.
// Sampling period ~1075cy (r17 was ~1500cy with 3 extra spacers).
__device__ __forceinline__ u64 poll_dual(const u64* fast, const u64* slow, int lane){
  const u64* pf = fast + lane;
  const u64* ps = slow + lane;
  u64 x = 0;
  for (int i = 0; i < BAIL; ++i){
    x = ld_sc0(pf);
    if (__all(x != POISON64)) return x;
    if (i & 1){
      x = ald(ps);
      if (__all(x != POISON64)) return x;
    }
    if (i > 16) __builtin_amdgcn_s_sleep(1);
  }
  return x;
}

// deposit u64 entry j=lane (comps 4j..4j+3) into padded h array
// (u64 chunk q at q*17: entry j -> (j>>4)*17 + (j&15)).
__device__ __forceinline__ void deposit64(u64* h8, int lane, u64 x){
  h8[(lane>>4)*17 + (lane&15)] = x;
}

__global__ __launch_bounds__(BT) void fused_kernel(
    const float* __restrict__ v0, const float* __restrict__ m0,
    const float* __restrict__ W1v, const float* __restrict__ b1v,
    const float* __restrict__ W1m, const float* __restrict__ b1m,
    const float* __restrict__ Wih_low, const float* __restrict__ Whh_low,
    const float* __restrict__ bih_low, const float* __restrict__ bhh_low,
    const float* __restrict__ Wih_high, const float* __restrict__ Whh_high,
    const float* __restrict__ bih_high, const float* __restrict__ bhh_high,
    const float* __restrict__ W2v, const float* __restrict__ b2v,
    const float* __restrict__ W2m, const float* __restrict__ b2m,
    float* __restrict__ out,
    u64* h1x, u64* h2x, u64* h1f, u64* h2f, u64* gxt, unsigned* ectl)
{
  // weights: 4 mats x 24 rows; row = 4 chunks of 16 u64 padded to 17 -> 68.
  __shared__ u64 wlds8[96*68];                  // 52224 B
  __shared__ u64 h1u8[68], h2u8[68];            // padded h (f16), 544 B each
  __shared__ float giA_l[24], ghA_l[24], giB_l[24], ghB_l[24];
  __shared__ float gx_lds[48];                  // [par][24]
  __shared__ float xbuf[H];
  __shared__ int s_role, s_idx;

  const int tid = threadIdx.x;
  const int wv = tid >> 6, lane = tid & 63;

  // ---------------- election: find one XCD with >=32 blocks (pigeonhole) ----
  if (tid == 0){
    unsigned xcd;
    asm volatile("s_getreg_b32 %0, hwreg(HW_REG_XCC_ID, 0, 32)" : "=s"(xcd));
    xcd &= 7u;
    unsigned tk = atomicAdd(&ectl[xcd], 1u);
    if (tk == 31u) atomicCAS(&ectl[8], 0u, xcd + 1u);
    unsigned ch; int guard = 0;
    while (!(ch = ald32(&ectl[8]))){
      __builtin_amdgcn_s_sleep(2);
      if (++guard > BAIL){ ch = 1u; break; }
    }
    if (xcd == ch - 1u && tk < 32u){ s_role = 0; s_idx = (int)tk; }
    else {
      unsigned ak = atomicAdd(&ectl[9], 1u);
      if      (ak < 50u ){ s_role = 1; s_idx = (int)ak; }
      else if (ak < 100u){ s_role = 2; s_idx = (int)(ak - 50u); }
      else               { s_role = 3; s_idx = 0; }
    }
  }
  __syncthreads();
  const int role = s_role, idx = s_idx;
  if (role == 3) return;

  if (role == 0){
    // ================================================== scan role
    const int b = idx;
    // stage weights: m: 0=Wih_low[:,256:512] 1=Whh_low 2=Wih_high 3=Whh_high
    for (int i = tid; i < 96*64; i += BT){
      int gr = i >> 6, c = i & 63;
      int m = gr / 24, lr = gr - m*24;
      int gate = lr >> 3, j = lr & 7;
      int row = gate*H + b*HJ + j;
      int k = c*4;
      float4 f;
      if      (m == 0) f = *(const float4*)(Wih_low  + (size_t)row*512 + 256 + k);
      else if (m == 1) f = *(const float4*)(Whh_low  + (size_t)row*256 + k);
      else if (m == 2) f = *(const float4*)(Wih_high + (size_t)row*256 + k);
      else             f = *(const float4*)(Whh_high + (size_t)row*256 + k);
      union{ u64 x; __half2 v[2]; } pk;
      pk.v[0] = __floats2half2_rn(f.x, f.y);
      pk.v[1] = __floats2half2_rn(f.z, f.w);
      wlds8[gr*68 + (c>>4)*17 + (c&15)] = pk.x;
    }
    if (tid < 24){ giA_l[tid]=0.f; ghA_l[tid]=0.f; giB_l[tid]=0.f; ghB_l[tid]=0.f; }

    float hv1 = 0.f, hv2 = 0.f;
    float blR=0,blZ=0,blN=0, biR=0,biZ=0,biN=0, bhR=0,bhZ=0,bhN=0;
    const int jg = b*HJ + lane;               // valid for lane<HJ
    if (wv == 0 && lane < HJ){
      blR = bhh_low [jg]; blZ = bhh_low [H+jg]; blN = bhh_low [2*H+jg];
      biR = bih_high[jg]; biZ = bih_high[H+jg]; biN = bih_high[2*H+jg];
      bhR = bhh_high[jg]; bhZ = bhh_high[H+jg]; bhN = bhh_high[2*H+jg];
      const u64* g = gxt + jg;                // Gx[0] -> gx_lds[0..23]
      int guard = 0;
      while (true){
        u64 a0 = ald(g), a1 = ald(g + H), a2 = ald(g + 2*H);
        bool ok = (((unsigned)(a0>>32))==1u) & (((unsigned)(a1>>32))==1u) & (((unsigned)(a2>>32))==1u);
        if (ok | (++guard > BAIL)){
          gx_lds[lane] = unpackv(a0); gx_lds[8+lane] = unpackv(a1); gx_lds[16+lane] = unpackv(a2);
          break;
        }
        __builtin_amdgcn_s_sleep(4);
      }
    }
    __syncthreads();

    const int gr = wv*16 + (lane >> 2);       // P-phase row (waves 0-2)
    const int q  = lane & 3;

    for (int t = 0; t < T_STEPS; ++t){
      const int par = t & 1;

      // ---- seg_a: wave0 finalize A + dual publish | wave1 Gx[t+1] | wave3 poll h1
      if (wv == 0){
        float hnew = hv1;
        if (lane < HJ){
          float giR = giA_l[lane]    + gx_lds[par*24 + lane];
          float giZ = giA_l[8+lane]  + gx_lds[par*24 + 8 + lane];
          float giN = giA_l[16+lane] + gx_lds[par*24 + 16 + lane];
          float ghR = ghA_l[lane]    + blR;
          float ghZ = ghA_l[8+lane]  + blZ;
          float ghN = ghA_l[16+lane] + blN;
          float r = sigm(giR + ghR), z = sigm(giZ + ghZ);
          float n = ftanh(giN + r * ghN);
          hv1 = (1.f - z) * n + z * hv1;
          hnew = hv1;
        }
        float pa = __shfl(hnew, 4*lane);
        float pb = __shfl(hnew, 4*lane + 1);
        float pc = __shfl(hnew, 4*lane + 2);
        float pd = __shfl(hnew, 4*lane + 3);
        if (lane < 2){
          union{ u64 x; __half2 v[2]; } pk;
          pk.v[0] = __floats2half2_rn(pa, pb);
          pk.v[1] = __floats2half2_rn(pc, pd);
          st_sc0(h1f + (size_t)t*64 + (b<<1) + lane, pk.x);   // spacer target
          ast  (h1x + (size_t)t*64 + (b<<1) + lane, pk.x);    // MALL (real path)
        }
      } else if (wv == 1){
        if (lane < HJ && t + 1 < T_STEPS){               // prefetch Gx[t+1]
          const u64* g = gxt + (size_t)(t+1)*G3 + jg;
          int guard = 0;
          while (true){
            u64 a0 = ald(g), a1 = ald(g + H), a2 = ald(g + 2*H);
            bool ok = (((unsigned)(a0>>32))==1u) & (((unsigned)(a1>>32))==1u) & (((unsigned)(a2>>32))==1u);
            if (ok | (++guard > BAIL)){
              int np = (1 - par) * 24;
              gx_lds[np + lane] = unpackv(a0); gx_lds[np + 8 + lane] = unpackv(a1); gx_lds[np + 16 + lane] = unpackv(a2);
              break;
            }
            __builtin_amdgcn_s_sleep(1);
          }
        }
      }
      if (t == T_STEPS - 1) break;
      if (wv == 3){
        u64 px = poll_dual(h1f + (size_t)t*64, h1x + (size_t)t*64, lane);
        deposit64(h1u8, lane, px);
      }
      __syncthreads();                                   // bar1: h1 ready

      // ---- P1: 48 rows on h1: gi_B (mat2) rows 0..23, gh_A' (mat1) rows 24..47
      if (wv < 3){
        int wr = (gr < 24) ? (48 + gr) : gr;             // mat2 base 48, mat1 base 24
        const u64* wrow = wlds8 + wr*68 + q*17;
        const u64* hh = h1u8 + q*17;
        float s = 0.f;
        #pragma unroll
        for (int i = 0; i < 16; ++i) s = dot4h(wrow[i], hh[i], s);
        s += __shfl_xor(s, 1);
        s += __shfl_xor(s, 2);
        if (q == 0){ if (gr < 24) giB_l[gr] = s; else ghA_l[gr-24] = s; }
      }
      __syncthreads();                                   // bar2: gi_B/gh_A' ready

      // ---- seg_b: wave0 finalize B + dual publish | wave3 poll h2
      if (wv == 0){
        float hnew = hv2;
        if (lane < HJ){
          float giR = giB_l[lane]    + biR, ghR = ghB_l[lane]    + bhR;
          float giZ = giB_l[8+lane]  + biZ, ghZ = ghB_l[8+lane]  + bhZ;
          float giN = giB_l[16+lane] + biN, ghN = ghB_l[16+lane] + bhN;
          float r = sigm(giR + ghR), z = sigm(giZ + ghZ);
          float n = ftanh(giN + r * ghN);
          hv2 = (1.f - z) * n + z * hv2;
          hnew = hv2;
        }
        float pa = __shfl(hnew, 4*lane);
        float pb = __shfl(hnew, 4*lane + 1);
        float pc = __shfl(hnew, 4*lane + 2);
        float pd = __shfl(hnew, 4*lane + 3);
        if (lane < 2){
          union{ u64 x; __half2 v[2]; } pk;
          pk.v[0] = __floats2half2_rn(pa, pb);
          pk.v[1] = __floats2half2_rn(pc, pd);
          st_sc0(h2f + (size_t)t*64 + (b<<1) + lane, pk.x);   // spacer target
          ast  (h2x + (size_t)t*64 + (b<<1) + lane, pk.x);    // MALL (real path)
        }
      } else if (wv == 3){
        u64 py = poll_dual(h2f + (size_t)t*64, h2x + (size_t)t*64, lane);
        deposit64(h2u8, lane, py);
      }
      __syncthreads();                                   // bar3: h2 ready

      // ---- P2: 48 rows on h2: gi_A' (mat0) rows 0..23, gh_B' (mat3) rows 24..47
      if (wv < 3){
        int wr = (gr < 24) ? gr : (48 + gr);             // mat0 base 0, mat3 base 72
        const u64* wrow = wlds8 + wr*68 + q*17;
        const u64* hh = h2u8 + q*17;
        float s = 0.f;
        #pragma unroll
        for (int i = 0; i < 16; ++i) s = dot4h(wrow[i], hh[i], s);
        s += __shfl_xor(s, 1);
        s += __shfl_xor(s, 2);
        if (q == 0){ if (gr < 24) giA_l[gr] = s; else ghB_l[gr-24] = s; }
      }
      __syncthreads();                                   // bar4
    }

  } else if (role == 1){
    // ================================================== featgx role
    const int t = idx;
    { int j = tid >> 1, s = tid & 1;
      const float4* a4 = reinterpret_cast<const float4*>(v0 + (size_t)t*VIN) + s*96;
      const float4* w4 = reinterpret_cast<const float4*>(W1v + (size_t)j*VIN) + s*96;
      float p = 0.f;
      #pragma unroll 4
      for (int c = 0; c < 96; ++c){
        float4 a = a4[c], w = w4[c];
        p += a.x*w.x + a.y*w.y + a.z*w.z + a.w*w.w;
      }
      p += __shfl_xor(p, 1);
      if (s == 0) xbuf[j] = eluf(p + b1v[j]);
    }
    if (tid < VF){
      float am = b1m[tid] + W1m[tid*2]*m0[t*2] + W1m[tid*2+1]*m0[t*2+1];
      xbuf[VF + tid] = eluf(am);
    }
    __syncthreads();
    #pragma unroll
    for (int k = 0; k < 3; ++k){
      int r = k*256 + tid;
      const float4* w4 = reinterpret_cast<const float4*>(Wih_low + (size_t)r*(2*H));
      const float4* x4 = reinterpret_cast<const float4*>(xbuf);
      float acc = bih_low[r];
      #pragma unroll 8
      for (int c = 0; c < 64; ++c){
        float4 w = w4[c], x = x4[c];
        acc += w.x*x.x + w.y*x.y + w.z*x.z + w.w*x.w;
      }
      ast(gxt + (size_t)t*G3 + r, packtv(1u, acc));
    }

  } else {
    // ================================================== post role
    const int t = idx;
    for (int i = 0; i < t; ++i) __builtin_amdgcn_s_sleep(32);   // staggered start
    if (wv == 0){
      // poison-poll h1x[t] (MALL copy ONLY — remote-L2 staleness trap).
      const u64* p = h1x + (size_t)t*64 + lane;
      u64 x = 0; int guard = 0;
      while (true){
        x = ald(p);
        if (__all(x != POISON64) | (++guard > BAIL)) break;
        __builtin_amdgcn_s_sleep(8);
      }
      union{ u64 v; __half2 h[2]; } c; c.v = x;
      float2 f0 = __half22float2(c.h[0]);
      float2 f1 = __half22float2(c.h[1]);
      xbuf[4*lane    ] = eluf(f0.x);
      xbuf[4*lane + 1] = eluf(f0.y);
      xbuf[4*lane + 2] = eluf(f1.x);
      xbuf[4*lane + 3] = eluf(f1.y);
    }
    __syncthreads();
    #pragma unroll
    for (int k = 0; k < 3; ++k){
      int r = k*256 + tid;
      const float4* w4 = reinterpret_cast<const float4*>(W2v + (size_t)r*VF);
      const float4* f4 = reinterpret_cast<const float4*>(xbuf);
      float acc = b2v[r];
      #pragma unroll 8
      for (int c = 0; c < 32; ++c){
        float4 w = w4[c], x = f4[c];
        acc += w.x*x.x + w.y*x.y + w.z*x.z + w.w*x.w;
      }
      out[(size_t)t*VIN + r] = sigm(acc);
    }
    if (tid < MIN_){
      const float* wm = W2m + tid*VF;
      float am = b2m[tid];
      #pragma unroll 8
      for (int c = 0; c < VF; ++c) am += wm[c] * xbuf[VF + c];
      out[(size_t)T_STEPS*VIN + t*MIN_ + tid] = tanhf(am);
    }
  }
}

extern "C" void kernel_launch(void* const* d_in, const int* in_sizes, int n_in,
                              void* d_out, int out_size, void* d_ws, size_t ws_size,
                              hipStream_t stream)
{
  const float* v0       = (const float*)d_in[0];
  const float* m0       = (const float*)d_in[1];
  const float* W1v      = (const float*)d_in[2];
  const float* b1v      = (const float*)d_in[3];
  const float* W1m      = (const float*)d_in[4];
  const float* b1m      = (const float*)d_in[5];
  const float* Wih_low  = (const float*)d_in[6];
  const float* Whh_low  = (const float*)d_in[7];
  const float* bih_low  = (const float*)d_in[8];
  const float* bhh_low  = (const float*)d_in[9];
  const float* Wih_high = (const float*)d_in[10];
  const float* Whh_high = (const float*)d_in[11];
  const float* bih_high = (const float*)d_in[12];
  const float* bhh_high = (const float*)d_in[13];
  const float* W2v      = (const float*)d_in[14];
  const float* b2v      = (const float*)d_in[15];
  const float* W2m      = (const float*)d_in[16];
  const float* b2m      = (const float*)d_in[17];
  float* out = (float*)d_out;

  // ws layout (8B-aligned).
  // h1x/h2x: [50][64] u64 MALL exchange buffers (agent-scope; the real path).
  // h1f/h2f: [50][64] u64 spacer-target buffers (stale L2 spins only).
  // All four poisoned 0xFF per launch (0xFFFF halfs = NaN, unreachable).
  // gxt: tagged (tag=1). Total ~410 KB (< proven 414 KB budget).
  char* ws = (char*)d_ws;
  u64* h1x      = (u64*)(ws + 0);               // 25600 B
  u64* h2x      = (u64*)(ws + 25600);           // 25600 B
  u64* h1f      = (u64*)(ws + 51200);           // 25600 B
  u64* h2f      = (u64*)(ws + 76800);           // 25600 B (ends 102400)
  u64* gxt      = (u64*)(ws + 102400);          // 307200 B (ends 409600)
  unsigned* ectl= (unsigned*)(ws + 409600);     // election state

  hipMemsetAsync(ws, 0xFF, 102400, stream);     // poison all exchange buffers
  hipMemsetAsync(ws + 409600, 0, 256, stream);  // zero election state

  fused_kernel<<<NBLOCKS, BT, 0, stream>>>(
      v0, m0, W1v, b1v, W1m, b1m,
      Wih_low, Whh_low, bih_low, bhh_low,
      Wih_high, Whh_high, bih_high, bhh_high,
      W2v, b2v, W2m, b2m, out,
      h1x, h2x, h1f, h2f, gxt, ectl);
}